// Round 8
// baseline (346.364 us; speedup 1.0000x reference)
//
#include <hip/hip_runtime.h>

#define N_NODES 4096
#define N_EDGES 131072
#define DIM     256
#define HEADS   8
#define HDIM    32
#define MAXDEG  320
#define MAXDEGP 321

typedef unsigned short u16;
typedef unsigned int   u32;

using f32x4  = __attribute__((ext_vector_type(4))) float;
using bf16x8 = __attribute__((ext_vector_type(8))) short;
using u16x8  = __attribute__((ext_vector_type(8))) unsigned short;

__device__ __forceinline__ u16 f2bf(float f) {
  u32 u = __float_as_uint(f);
  u += 0x7fffu + ((u >> 16) & 1u);   // RNE
  return (u16)(u >> 16);
}

__device__ __forceinline__ float dot4(float4 a, float4 b) {
  return a.x * b.x + a.y * b.y + a.z * b.z + a.w * b.w;
}

// ---------------------------------------------------------------------------
// Weight prep
// ---------------------------------------------------------------------------
__global__ __launch_bounds__(256) void prep_w_k(
    const float* __restrict__ Wq, const float* __restrict__ Wk,
    const float* __restrict__ Wv, const float* __restrict__ Wi,
    const float* __restrict__ We, const float* __restrict__ Wo,
    const float* __restrict__ bq, const float* __restrict__ bk,
    const float* __restrict__ bv, const float* __restrict__ bi,
    u16* __restrict__ WcatT, u16* __restrict__ WeT, u16* __restrict__ WoT,
    float* __restrict__ bcat)
{
  int n = blockIdx.x;
  int k = threadIdx.x;
  if (n < 1024) {
    const float* W = (n < 256) ? Wq : (n < 512) ? Wk : (n < 768) ? Wv : Wi;
    int nn = n & 255;
    WcatT[(size_t)n * 256 + k] = f2bf(W[(size_t)k * 256 + nn]);
    if (k == 0) {
      const float* b = (n < 256) ? bq : (n < 512) ? bk : (n < 768) ? bv : bi;
      bcat[n] = b[nn];
    }
  } else if (n < 1280) {
    int nn = n - 1024;
    WeT[(size_t)nn * 256 + k] = f2bf(We[(size_t)k * 256 + nn]);
  } else {
    int nn = n - 1280;
    WoT[(size_t)nn * 256 + k] = f2bf(Wo[(size_t)k * 256 + nn]);
  }
}

// ---------------------------------------------------------------------------
// Wave-autonomous GEMM: one wave computes C[r0..r0+16)[c0..c0+64).
// NO LDS, NO barriers, NO cross-lane. Lane (fr,hi) loads its entire MFMA
// a-fragment set for ALL 8 K-steps upfront (16 float4, coalesced: 16 rows x
// 128B per chunk) -> max memory-level parallelism, pipeline never drains.
// fp32 -> bf16 conversion per K-step in registers. B (bf16, L2-hot) loaded
// one K-step ahead. mfma(b, a, acc) => lane holds C[m=fr][n=ni*16+hi*4+reg].
// ---------------------------------------------------------------------------
__device__ __forceinline__ void wgemm16_body(
    const float* __restrict__ A, const u16* __restrict__ BT,
    const float* __restrict__ bias, float* __restrict__ C,
    int Nn, int r0, int c0)
{
  const int l = threadIdx.x & 63;
  const int fr = l & 15, hi = l >> 4;
  const float* Ap = A + (size_t)(r0 + fr) * 256 + hi * 8;
  const u16*   Bp = BT + (size_t)(c0 + fr) * 256 + hi * 8;

  // all A loads for the whole K range, issued back-to-back
  float4 pa[16];
#pragma unroll
  for (int kt = 0; kt < 8; ++kt) {
    pa[2 * kt]     = *(const float4*)(Ap + kt * 32);
    pa[2 * kt + 1] = *(const float4*)(Ap + kt * 32 + 4);
  }

  bf16x8 pb[2][4];
#pragma unroll
  for (int ni = 0; ni < 4; ++ni)
    pb[0][ni] = *(const bf16x8*)(Bp + (size_t)ni * 16 * 256);

  f32x4 acc[4] = {};
#pragma unroll
  for (int kt = 0; kt < 8; ++kt) {
    const int cur = kt & 1;
    if (kt < 7) {
#pragma unroll
      for (int ni = 0; ni < 4; ++ni)
        pb[cur ^ 1][ni] =
            *(const bf16x8*)(Bp + (size_t)ni * 16 * 256 + (kt + 1) * 32);
    }
    float4 x0 = pa[2 * kt], x1 = pa[2 * kt + 1];
    u16x8 u;
    u[0] = f2bf(x0.x); u[1] = f2bf(x0.y); u[2] = f2bf(x0.z); u[3] = f2bf(x0.w);
    u[4] = f2bf(x1.x); u[5] = f2bf(x1.y); u[6] = f2bf(x1.z); u[7] = f2bf(x1.w);
    bf16x8 a = *(bf16x8*)&u;
#pragma unroll
    for (int ni = 0; ni < 4; ++ni)
      acc[ni] = __builtin_amdgcn_mfma_f32_16x16x32_bf16(
          pb[cur][ni], a, acc[ni], 0, 0, 0);
  }

  const int row = r0 + fr;
#pragma unroll
  for (int ni = 0; ni < 4; ++ni) {
    int col = c0 + ni * 16 + hi * 4;
    float4 bv = *(const float4*)&bias[col];
    f32x4 v = acc[ni];
    float4 o;
    o.x = v[0] + bv.x; o.y = v[1] + bv.y; o.z = v[2] + bv.z; o.w = v[3] + bv.w;
    *(float4*)&C[(size_t)row * Nn + col] = o;
  }
}

// Merged dispatch: 36864 wave-jobs = 32768 edge (E/16 stripes x 4 col-quarters)
// + 4096 QKVI (N/16 stripes x 16 col-quarters), interleaved 8:1 per wave.
__global__ __launch_bounds__(256) void gemm_all_k(
    const float* __restrict__ ea, const u16* __restrict__ WeT,
    const float* __restrict__ be, float* __restrict__ outE,
    const float* __restrict__ x, const u16* __restrict__ WcatT,
    const float* __restrict__ bcat, float* __restrict__ QKVI)
{
  int g = blockIdx.x * 4 + (threadIdx.x >> 6);
  int r = g % 9, q = g / 9;
  if (r < 8) {
    int j = q * 8 + r;                       // 0..32767
    wgemm16_body(ea, WeT, be, outE, 256, (j >> 2) * 16, (j & 3) * 64);
  } else {
    wgemm16_body(x, WcatT, bcat, QKVI, 1024, (q >> 4) * 16, (q & 15) * 64);
  }
}

// Standalone (Wo projection): 1024 wave-jobs
__global__ __launch_bounds__(256) void gemmWo_k(
    const float* __restrict__ agg, const u16* __restrict__ WoT,
    const float* __restrict__ bo, float* __restrict__ preo)
{
  int g = blockIdx.x * 4 + (threadIdx.x >> 6);
  wgemm16_body(agg, WoT, bo, preo, 256, (g >> 2) * 16, (g & 3) * 64);
}

// ---------------------------------------------------------------------------
// CSR build
// ---------------------------------------------------------------------------
__global__ __launch_bounds__(256) void hist_k(const int* __restrict__ src, int* __restrict__ deg)
{
  int e = blockIdx.x * 256 + threadIdx.x;
  if (e < N_EDGES) atomicAdd(&deg[src[e]], 1);
}

__global__ __launch_bounds__(1024) void scan_k(const int* __restrict__ deg,
                                               int* __restrict__ rowstart,
                                               int* __restrict__ cursor)
{
  __shared__ int s[1024];
  int tid = threadIdx.x;
  int4 v = ((const int4*)deg)[tid];
  int sum = v.x + v.y + v.z + v.w;
  s[tid] = sum;
  __syncthreads();
  for (int off = 1; off < 1024; off <<= 1) {
    int t = (tid >= off) ? s[tid - off] : 0;
    __syncthreads();
    s[tid] += t;
    __syncthreads();
  }
  int excl = s[tid] - sum;
  int r0 = excl, r1 = excl + v.x, r2 = r1 + v.y, r3 = r2 + v.z;
  rowstart[4 * tid + 0] = r0; cursor[4 * tid + 0] = r0;
  rowstart[4 * tid + 1] = r1; cursor[4 * tid + 1] = r1;
  rowstart[4 * tid + 2] = r2; cursor[4 * tid + 2] = r2;
  rowstart[4 * tid + 3] = r3; cursor[4 * tid + 3] = r3;
  if (tid == 1023) rowstart[4096] = r3 + v.w;
}

__global__ __launch_bounds__(256) void scatter_k(const int* __restrict__ src,
                                                 int* __restrict__ cursor,
                                                 int* __restrict__ csr)
{
  int e = blockIdx.x * 256 + threadIdx.x;
  if (e < N_EDGES) {
    int p = atomicAdd(&cursor[src[e]], 1);
    csr[p] = e;
  }
}

// ---------------------------------------------------------------------------
// Fused per-node kernel: edge logits + sparse softmax + V aggregation.
// ---------------------------------------------------------------------------
__global__ __launch_bounds__(256) void node_attn_k(
    const float* __restrict__ QKVI, const float* __restrict__ Ef,
    const int* __restrict__ rowstart, const int* __restrict__ csr,
    const int* __restrict__ tgt, float* __restrict__ agg)
{
  __shared__ int   s_eid[MAXDEG];
  __shared__ int   s_tgt[MAXDEG];
  __shared__ float s_sc[HEADS][MAXDEGP];   // scores, then weights in-place
  __shared__ unsigned char s_alive[MAXDEG];
  __shared__ float s_self[8];
  __shared__ float s_wself[8];

  const float scl = 0.17677669529663687f;
  int i = blockIdx.x;
  int base = rowstart[i];
  int deg = rowstart[i + 1] - base;
  if (deg > MAXDEG) deg = MAXDEG;
  int tid = threadIdx.x;
  int w = tid >> 6, l = tid & 63;
  int h = tid >> 5, d = tid & 31;

  for (int t = tid; t < deg; t += 256) {
    int e = csr[base + t];
    s_eid[t] = e;
    s_tgt[t] = tgt[e];
  }
  __syncthreads();

  // Q_i: lane l holds dims 4l..4l+3 (head = l>>3)
  float4 q4 = *(const float4*)&QKVI[(size_t)i * 1024 + 4 * l];

  // self score (wave 0): Q_i . K_i per head
  if (w == 0) {
    float4 k4 = *(const float4*)&QKVI[(size_t)i * 1024 + 256 + 4 * l];
    float c = dot4(q4, k4);
#pragma unroll
    for (int off = 1; off <= 4; off <<= 1) c += __shfl_xor(c, off);
    if ((l & 7) == 0) s_self[l >> 3] = c * scl;
  }

  // edge logits: waves split edges; logit = ef.(q+k) + q.k per head
  for (int t = w; t < deg; t += 4) {
    int e = s_eid[t], tt = s_tgt[t];
    float4 ef = *(const float4*)&Ef[(size_t)e * 256 + 4 * l];
    float4 k4 = *(const float4*)&QKVI[(size_t)tt * 1024 + 256 + 4 * l];
    float c = dot4(q4, ef) + dot4(ef, k4) + dot4(q4, k4);
#pragma unroll
    for (int off = 1; off <= 4; off <<= 1) c += __shfl_xor(c, off);
    if ((l & 7) == 0) s_sc[l >> 3][t] = c * scl;
  }

  // dedup (keep max eid per tgt), drop self-target
  for (int t = tid; t < deg; t += 256) {
    int tt = s_tgt[t], ee = s_eid[t];
    bool alive = (tt != i);
    if (alive)
      for (int u = 0; u < deg; ++u)
        if (s_tgt[u] == tt && s_eid[u] > ee) { alive = false; break; }
    s_alive[t] = alive ? 1 : 0;
  }
  __syncthreads();

  // softmax: 32 lanes per head, in-place weights
  {
    float m = s_self[h];
    for (int t = d; t < deg; t += 32)
      if (s_alive[t]) m = fmaxf(m, s_sc[h][t]);
#pragma unroll
    for (int off = 16; off > 0; off >>= 1) m = fmaxf(m, __shfl_xor(m, off, 32));
    float lsum = 0.f;
    for (int t = d; t < deg; t += 32) {
      float wv = s_alive[t] ? expf(s_sc[h][t] - m) : 0.f;
      s_sc[h][t] = wv;
      lsum += wv;
    }
#pragma unroll
    for (int off = 16; off > 0; off >>= 1) lsum += __shfl_xor(lsum, off, 32);
    float wself = expf(s_self[h] - m);
    float inv = 1.f / (lsum + wself);
    if (d == 0) s_wself[h] = wself * inv;
    for (int t = d; t < deg; t += 32) s_sc[h][t] *= inv;
  }
  __syncthreads();

  // aggregate V (cols 512..767 of QKVI); col = tid -> coalesced
  int col = tid;
  float accv = s_wself[h] * QKVI[(size_t)i * 1024 + 512 + col];
  for (int t = 0; t < deg; ++t)
    if (s_alive[t])
      accv += s_sc[h][t] * QKVI[(size_t)s_tgt[t] * 1024 + 512 + col];
  agg[(size_t)i * 256 + col] = accv;
}

// ---------------------------------------------------------------------------
// LayerNorm(x_proj + preo)
// ---------------------------------------------------------------------------
__global__ __launch_bounds__(256) void ln_k(
    const float* __restrict__ QKVI, const float* __restrict__ preo,
    const float* __restrict__ g, const float* __restrict__ b,
    float* __restrict__ out)
{
  int i = blockIdx.x, c = threadIdx.x;
  float v = QKVI[(size_t)i * 1024 + 768 + c] + preo[(size_t)i * 256 + c];
  float s1 = v, s2 = v * v;
#pragma unroll
  for (int off = 32; off > 0; off >>= 1) {
    s1 += __shfl_xor(s1, off, 64);
    s2 += __shfl_xor(s2, off, 64);
  }
  __shared__ float r1[4], r2[4];
  int w = c >> 6;
  if ((c & 63) == 0) { r1[w] = s1; r2[w] = s2; }
  __syncthreads();
  s1 = r1[0] + r1[1] + r1[2] + r1[3];
  s2 = r2[0] + r2[1] + r2[2] + r2[3];
  float mu  = s1 * (1.0f / 256.0f);
  float var = s2 * (1.0f / 256.0f) - mu * mu;
  out[(size_t)i * 256 + c] = (v - mu) * rsqrtf(var + 1e-5f) * g[c] + b[c];
}

// ---------------------------------------------------------------------------
extern "C" void kernel_launch(void* const* d_in, const int* in_sizes, int n_in,
                              void* d_out, int out_size, void* d_ws, size_t ws_size,
                              hipStream_t stream) {
  (void)in_sizes; (void)n_in; (void)out_size; (void)ws_size;
  const float* x  = (const float*)d_in[0];
  const int*   ei = (const int*)d_in[1];
  const float* ea = (const float*)d_in[2];
  const float* Wq = (const float*)d_in[3];  const float* bq = (const float*)d_in[4];
  const float* Wk = (const float*)d_in[5];  const float* bk = (const float*)d_in[6];
  const float* Wv = (const float*)d_in[7];  const float* bv = (const float*)d_in[8];
  const float* We = (const float*)d_in[9];  const float* be = (const float*)d_in[10];
  const float* Wo = (const float*)d_in[11]; const float* bo = (const float*)d_in[12];
  const float* Wi = (const float*)d_in[13]; const float* bi = (const float*)d_in[14];
  const float* lng = (const float*)d_in[15]; const float* lnb = (const float*)d_in[16];

  const int* src = ei;
  const int* tgt = ei + N_EDGES;

  char* ws = (char*)d_ws;
  u16*   WcatT   = (u16*)(ws + 0);              //  512 KB
  u16*   WeT     = (u16*)(ws + 524288);         //  128 KB
  u16*   WoT     = (u16*)(ws + 655360);         //  128 KB
  float* bcat    = (float*)(ws + 786432);       //    4 KB
  float* QKVI    = (float*)(ws + 790528);       //   16 MB
  int*   deg     = (int*)(ws + 17567744);       //   16 KB
  int*   rowstart= (int*)(ws + 17584128);       //   16.25 KB
  int*   cursor  = (int*)(ws + 17600768);       //   16 KB
  int*   csr     = (int*)(ws + 17617152);       //  512 KB
  float* agg     = (float*)(ws + 18141440);     //    4 MB
  float* preo    = (float*)(ws + 22335744);     //    4 MB

  float* outN = (float*)d_out;
  float* outE = (float*)d_out + (size_t)N_NODES * DIM;

  hipMemsetAsync(deg, 0, N_NODES * sizeof(int), stream);

  prep_w_k<<<1536, 256, 0, stream>>>(Wq, Wk, Wv, Wi, We, Wo, bq, bk, bv, bi,
                                     WcatT, WeT, WoT, bcat);

  hist_k<<<N_EDGES / 256, 256, 0, stream>>>(src, deg);
  scan_k<<<1, 1024, 0, stream>>>(deg, rowstart, cursor);
  scatter_k<<<N_EDGES / 256, 256, 0, stream>>>(src, cursor, csr);

  // merged: edge_out = ea @ We + be  AND  QKVI = x @ [Wq|Wk|Wv|Wi] + bcat
  gemm_all_k<<<9216, 256, 0, stream>>>(ea, WeT, be, outE, x, WcatT, bcat, QKVI);

  // fused logits + softmax + V aggregation
  node_attn_k<<<N_NODES, 256, 0, stream>>>(QKVI, outE, rowstart, csr, tgt, agg);

  // preo = agg @ Wo + bo
  gemmWo_k<<<256, 256, 0, stream>>>(agg, WoT, bo, preo);

  ln_k<<<N_NODES, 256, 0, stream>>>(QKVI, preo, lng, lnb, outN);
}

// Round 10
// 215.805 us; speedup vs baseline: 1.6050x; 1.6050x over previous
//
#include <hip/hip_runtime.h>

#define N_NODES 4096
#define N_EDGES 131072
#define DIM     256
#define HEADS   8
#define HDIM    32
#define MAXW    128      // per-node edge cap (Poisson λ=32; P(deg>128) ~ 1e-30)
#define MAXWP   132      // padded stride: (132h+t)%32 = 4h+t -> heads hit distinct banks

typedef unsigned short u16;
typedef unsigned int   u32;

using f32x4  = __attribute__((ext_vector_type(4))) float;
using bf16x8 = __attribute__((ext_vector_type(8))) short;
using u16x4  = __attribute__((ext_vector_type(4))) unsigned short;
using u16x8  = __attribute__((ext_vector_type(8))) unsigned short;

__device__ __forceinline__ u16 f2bf(float f) {
  u32 u = __float_as_uint(f);
  u += 0x7fffu + ((u >> 16) & 1u);   // RNE
  return (u16)(u >> 16);
}

__device__ __forceinline__ float dot4(float4 a, float4 b) {
  return a.x * b.x + a.y * b.y + a.z * b.z + a.w * b.w;
}

// ---------------------------------------------------------------------------
// Weight prep
// ---------------------------------------------------------------------------
__global__ __launch_bounds__(256) void prep_w_k(
    const float* __restrict__ Wq, const float* __restrict__ Wk,
    const float* __restrict__ Wv, const float* __restrict__ Wi,
    const float* __restrict__ We, const float* __restrict__ Wo,
    const float* __restrict__ bq, const float* __restrict__ bk,
    const float* __restrict__ bv, const float* __restrict__ bi,
    u16* __restrict__ WcatT, u16* __restrict__ WeT, u16* __restrict__ WoT,
    float* __restrict__ bcat)
{
  int n = blockIdx.x;
  int k = threadIdx.x;
  if (n < 1024) {
    const float* W = (n < 256) ? Wq : (n < 512) ? Wk : (n < 768) ? Wv : Wi;
    int nn = n & 255;
    WcatT[(size_t)n * 256 + k] = f2bf(W[(size_t)k * 256 + nn]);
    if (k == 0) {
      const float* b = (n < 256) ? bq : (n < 512) ? bk : (n < 768) ? bv : bi;
      bcat[n] = b[nn];
    }
  } else if (n < 1280) {
    int nn = n - 1024;
    WeT[(size_t)nn * 256 + k] = f2bf(We[(size_t)k * 256 + nn]);
  } else {
    int nn = n - 1280;
    WoT[(size_t)nn * 256 + k] = f2bf(Wo[(size_t)k * 256 + nn]);
  }
}

// ---------------------------------------------------------------------------
// 128x128 GEMM (proven 88us structure): C = A(fp32) @ B + bias, BT = B^T bf16.
// LDS dbuf, reg prefetch, lgkmcnt-only barrier, XOR swizzle. Lane holds
// C[m=mi*16+fr][n=ni*16+hi*4+reg] via mfma(b,a,acc) swap -> float4 stores.
// ---------------------------------------------------------------------------
__global__ __launch_bounds__(256) void gemm3_k(
    const float* __restrict__ Afp, const u16* __restrict__ BT,
    const float* __restrict__ bias, float* __restrict__ C, int Nn)
{
  __shared__ u16 As[2][128 * 32];
  __shared__ u16 Bs[2][128 * 32];
  const int n0 = blockIdx.x * 128;
  const int m0 = blockIdx.y * 128;
  const int tid = threadIdx.x;
  const int w = tid >> 6, l = tid & 63;
  const int wr = w >> 1, wc = w & 1;
  const int fr = l & 15, hi = l >> 4;

  float4 pa[4];
  u16x8  pb[2];
  f32x4  acc[4][4] = {};

  auto loadstep = [&](int kt) {
#pragma unroll
    for (int i = 0; i < 4; ++i) {
      int j = tid + 256 * i;
      pa[i] = *(const float4*)(Afp + (size_t)(m0 + (j >> 3)) * 256 + kt * 32 + ((j & 7) << 2));
    }
#pragma unroll
    for (int i = 0; i < 2; ++i) {
      int j = tid + 256 * i;
      pb[i] = *(const u16x8*)(BT + (size_t)(n0 + (j >> 2)) * 256 + kt * 32 + ((j & 3) << 3));
    }
  };
  auto storestep = [&](int buf) {
#pragma unroll
    for (int i = 0; i < 4; ++i) {
      int j = tid + 256 * i;
      int row = j >> 3;
      int c16 = (j & 7) >> 1, half = j & 1;
      int swc = (c16 + ((row >> 1) & 3)) & 3;
      u16x4 u;
      u.x = f2bf(pa[i].x); u.y = f2bf(pa[i].y); u.z = f2bf(pa[i].z); u.w = f2bf(pa[i].w);
      *(u16x4*)&As[buf][row * 32 + swc * 8 + half * 4] = u;
    }
#pragma unroll
    for (int i = 0; i < 2; ++i) {
      int j = tid + 256 * i;
      int row = j >> 2;
      int swc = ((j & 3) + ((row >> 1) & 3)) & 3;
      *(u16x8*)&Bs[buf][row * 32 + swc * 8] = pb[i];
    }
  };

  loadstep(0);
  storestep(0);

#pragma unroll
  for (int kt = 0; kt < 8; ++kt) {
    if (kt < 7) loadstep(kt + 1);
    __builtin_amdgcn_sched_barrier(0);
    asm volatile("s_waitcnt lgkmcnt(0)" ::: "memory");
    __builtin_amdgcn_s_barrier();
    __builtin_amdgcn_sched_barrier(0);
    const int cur = kt & 1;
    bf16x8 a[4], b[4];
#pragma unroll
    for (int mi = 0; mi < 4; ++mi) {
      int rA = wr * 64 + mi * 16 + fr;
      int swc = (hi + ((rA >> 1) & 3)) & 3;
      a[mi] = *(const bf16x8*)&As[cur][rA * 32 + swc * 8];
    }
#pragma unroll
    for (int ni = 0; ni < 4; ++ni) {
      int rB = wc * 64 + ni * 16 + fr;
      int swc = (hi + ((rB >> 1) & 3)) & 3;
      b[ni] = *(const bf16x8*)&Bs[cur][rB * 32 + swc * 8];
    }
#pragma unroll
    for (int mi = 0; mi < 4; ++mi)
#pragma unroll
      for (int ni = 0; ni < 4; ++ni)
        acc[mi][ni] = __builtin_amdgcn_mfma_f32_16x16x32_bf16(
            b[ni], a[mi], acc[mi][ni], 0, 0, 0);
    if (kt < 7) storestep((kt + 1) & 1);
  }

#pragma unroll
  for (int mi = 0; mi < 4; ++mi) {
    int row = m0 + wr * 64 + mi * 16 + fr;
#pragma unroll
    for (int ni = 0; ni < 4; ++ni) {
      int col = n0 + wc * 64 + ni * 16 + hi * 4;
      float4 bv = *(const float4*)&bias[col];
      f32x4 v = acc[mi][ni];
      float4 o;
      o.x = v[0] + bv.x; o.y = v[1] + bv.y; o.z = v[2] + bv.z; o.w = v[3] + bv.w;
      *(float4*)&C[(size_t)row * Nn + col] = o;
    }
  }
}

// ---------------------------------------------------------------------------
// CSR build
// ---------------------------------------------------------------------------
__global__ __launch_bounds__(256) void hist_k(const int* __restrict__ src, int* __restrict__ deg)
{
  int e = blockIdx.x * 256 + threadIdx.x;
  if (e < N_EDGES) atomicAdd(&deg[src[e]], 1);
}

__global__ __launch_bounds__(1024) void scan_k(const int* __restrict__ deg,
                                               int* __restrict__ rowstart,
                                               int* __restrict__ cursor)
{
  __shared__ int s[1024];
  int tid = threadIdx.x;
  int4 v = ((const int4*)deg)[tid];
  int sum = v.x + v.y + v.z + v.w;
  s[tid] = sum;
  __syncthreads();
  for (int off = 1; off < 1024; off <<= 1) {
    int t = (tid >= off) ? s[tid - off] : 0;
    __syncthreads();
    s[tid] += t;
    __syncthreads();
  }
  int excl = s[tid] - sum;
  int r0 = excl, r1 = excl + v.x, r2 = r1 + v.y, r3 = r2 + v.z;
  rowstart[4 * tid + 0] = r0; cursor[4 * tid + 0] = r0;
  rowstart[4 * tid + 1] = r1; cursor[4 * tid + 1] = r1;
  rowstart[4 * tid + 2] = r2; cursor[4 * tid + 2] = r2;
  rowstart[4 * tid + 3] = r3; cursor[4 * tid + 3] = r3;
  if (tid == 1023) rowstart[4096] = r3 + v.w;
}

__global__ __launch_bounds__(256) void scatter_k(const int* __restrict__ src,
                                                 int* __restrict__ cursor,
                                                 int* __restrict__ csr)
{
  int e = blockIdx.x * 256 + threadIdx.x;
  if (e < N_EDGES) {
    int p = atomicAdd(&cursor[src[e]], 1);
    csr[p] = e;
  }
}

// ---------------------------------------------------------------------------
// Wave-per-node fused kernel: edge logits + sparse softmax + V aggregation.
// 4 nodes per 256-thread block, one wave each. Lane l holds dims 4l..4l+3
// (head h = l>>3, 8 lanes/head). All reductions via 3-level __shfl_xor in
// the 8-lane group. Barriers only at 3 phase boundaries.
// ---------------------------------------------------------------------------
__global__ __launch_bounds__(256) void node_attn_k(
    const float* __restrict__ QKVI, const float* __restrict__ Ef,
    const int* __restrict__ rowstart, const int* __restrict__ csr,
    const int* __restrict__ tgt, float* __restrict__ agg)
{
  __shared__ int   s_eid[4][MAXW];
  __shared__ int   s_tgt[4][MAXW];
  __shared__ float s_sc[4][HEADS][MAXWP];
  __shared__ unsigned char s_alive[4][MAXW];
  __shared__ float s_self[4][8];
  __shared__ float s_wself[4][8];

  const float scl = 0.17677669529663687f;
  const int w = threadIdx.x >> 6, l = threadIdx.x & 63;
  const int i = blockIdx.x * 4 + w;
  const int h = l >> 3, d8 = l & 7;
  int base = rowstart[i];
  int deg = rowstart[i + 1] - base;
  if (deg > MAXW) deg = MAXW;

  for (int t = l; t < deg; t += 64) {
    int e = csr[base + t];
    s_eid[w][t] = e;
    s_tgt[w][t] = tgt[e];
  }
  __syncthreads();

  // Q_i: lane l holds dims 4l..4l+3
  float4 q4 = *(const float4*)&QKVI[(size_t)i * 1024 + 4 * l];

  // self score
  {
    float4 k4 = *(const float4*)&QKVI[(size_t)i * 1024 + 256 + 4 * l];
    float c = dot4(q4, k4);
    c += __shfl_xor(c, 1); c += __shfl_xor(c, 2); c += __shfl_xor(c, 4);
    if (d8 == 0) s_self[w][h] = c * scl;
  }

  // edge logits: whole wave per edge, 8 heads in parallel
  for (int t = 0; t < deg; ++t) {
    int e = s_eid[w][t], tt = s_tgt[w][t];
    float4 ef = *(const float4*)&Ef[(size_t)e * 256 + 4 * l];
    float4 k4 = *(const float4*)&QKVI[(size_t)tt * 1024 + 256 + 4 * l];
    float c = dot4(q4, ef) + dot4(ef, k4) + dot4(q4, k4);
    c += __shfl_xor(c, 1); c += __shfl_xor(c, 2); c += __shfl_xor(c, 4);
    if (d8 == 0) s_sc[w][h][t] = c * scl;
  }

  // dedup (keep max eid per tgt), drop self-target
  for (int t = l; t < deg; t += 64) {
    int tt = s_tgt[w][t], ee = s_eid[w][t];
    bool alive = (tt != i);
    if (alive)
      for (int u = 0; u < deg; ++u)
        if (s_tgt[w][u] == tt && s_eid[w][u] > ee) { alive = false; break; }
    s_alive[w][t] = alive ? 1 : 0;
  }
  __syncthreads();

  // softmax: 8 lanes per head
  {
    float m = s_self[w][h];
    for (int t = d8; t < deg; t += 8)
      if (s_alive[w][t]) m = fmaxf(m, s_sc[w][h][t]);
    m = fmaxf(m, __shfl_xor(m, 1)); m = fmaxf(m, __shfl_xor(m, 2)); m = fmaxf(m, __shfl_xor(m, 4));
    float lsum = 0.f;
    for (int t = d8; t < deg; t += 8) {
      float wv = s_alive[w][t] ? expf(s_sc[w][h][t] - m) : 0.f;
      s_sc[w][h][t] = wv;
      lsum += wv;
    }
    lsum += __shfl_xor(lsum, 1); lsum += __shfl_xor(lsum, 2); lsum += __shfl_xor(lsum, 4);
    float wself = expf(s_self[w][h] - m);
    float inv = 1.f / (lsum + wself);
    if (d8 == 0) s_wself[w][h] = wself * inv;
    for (int t = d8; t < deg; t += 8) s_sc[w][h][t] *= inv;
  }
  __syncthreads();

  // aggregate V: lane l accumulates cols 4l..4l+3 as float4
  float4 vv = *(const float4*)&QKVI[(size_t)i * 1024 + 512 + 4 * l];
  float ws = s_wself[w][h];
  float a0 = ws * vv.x, a1 = ws * vv.y, a2 = ws * vv.z, a3 = ws * vv.w;
  for (int t = 0; t < deg; ++t) {
    if (s_alive[w][t]) {
      float wt = s_sc[w][h][t];   // broadcast within 8-lane group
      float4 v4 = *(const float4*)&QKVI[(size_t)s_tgt[w][t] * 1024 + 512 + 4 * l];
      a0 += wt * v4.x; a1 += wt * v4.y; a2 += wt * v4.z; a3 += wt * v4.w;
    }
  }
  float4 o; o.x = a0; o.y = a1; o.z = a2; o.w = a3;
  *(float4*)&agg[(size_t)i * 256 + 4 * l] = o;
}

// ---------------------------------------------------------------------------
// LayerNorm(x_proj + preo)
// ---------------------------------------------------------------------------
__global__ __launch_bounds__(256) void ln_k(
    const float* __restrict__ QKVI, const float* __restrict__ preo,
    const float* __restrict__ g, const float* __restrict__ b,
    float* __restrict__ out)
{
  int i = blockIdx.x, c = threadIdx.x;
  float v = QKVI[(size_t)i * 1024 + 768 + c] + preo[(size_t)i * 256 + c];
  float s1 = v, s2 = v * v;
#pragma unroll
  for (int off = 32; off > 0; off >>= 1) {
    s1 += __shfl_xor(s1, off, 64);
    s2 += __shfl_xor(s2, off, 64);
  }
  __shared__ float r1[4], r2[4];
  int w = c >> 6;
  if ((c & 63) == 0) { r1[w] = s1; r2[w] = s2; }
  __syncthreads();
  s1 = r1[0] + r1[1] + r1[2] + r1[3];
  s2 = r2[0] + r2[1] + r2[2] + r2[3];
  float mu  = s1 * (1.0f / 256.0f);
  float var = s2 * (1.0f / 256.0f) - mu * mu;
  out[(size_t)i * 256 + c] = (v - mu) * rsqrtf(var + 1e-5f) * g[c] + b[c];
}

// ---------------------------------------------------------------------------
extern "C" void kernel_launch(void* const* d_in, const int* in_sizes, int n_in,
                              void* d_out, int out_size, void* d_ws, size_t ws_size,
                              hipStream_t stream) {
  (void)in_sizes; (void)n_in; (void)out_size; (void)ws_size;
  const float* x  = (const float*)d_in[0];
  const int*   ei = (const int*)d_in[1];
  const float* ea = (const float*)d_in[2];
  const float* Wq = (const float*)d_in[3];  const float* bq = (const float*)d_in[4];
  const float* Wk = (const float*)d_in[5];  const float* bk = (const float*)d_in[6];
  const float* Wv = (const float*)d_in[7];  const float* bv = (const float*)d_in[8];
  const float* We = (const float*)d_in[9];  const float* be = (const float*)d_in[10];
  const float* Wo = (const float*)d_in[11]; const float* bo = (const float*)d_in[12];
  const float* Wi = (const float*)d_in[13]; const float* bi = (const float*)d_in[14];
  const float* lng = (const float*)d_in[15]; const float* lnb = (const float*)d_in[16];

  const int* src = ei;
  const int* tgt = ei + N_EDGES;

  char* ws = (char*)d_ws;
  u16*   WcatT   = (u16*)(ws + 0);              //  512 KB
  u16*   WeT     = (u16*)(ws + 524288);         //  128 KB
  u16*   WoT     = (u16*)(ws + 655360);         //  128 KB
  float* bcat    = (float*)(ws + 786432);       //    4 KB
  float* QKVI    = (float*)(ws + 790528);       //   16 MB
  int*   deg     = (int*)(ws + 17567744);       //   16 KB
  int*   rowstart= (int*)(ws + 17584128);       //   16.25 KB
  int*   cursor  = (int*)(ws + 17600768);       //   16 KB
  int*   csr     = (int*)(ws + 17617152);       //  512 KB
  float* agg     = (float*)(ws + 18141440);     //    4 MB
  float* preo    = (float*)(ws + 22335744);     //    4 MB

  float* outN = (float*)d_out;
  float* outE = (float*)d_out + (size_t)N_NODES * DIM;

  (void)hipMemsetAsync(deg, 0, N_NODES * sizeof(int), stream);

  prep_w_k<<<1536, 256, 0, stream>>>(Wq, Wk, Wv, Wi, We, Wo, bq, bk, bv, bi,
                                     WcatT, WeT, WoT, bcat);

  hist_k<<<N_EDGES / 256, 256, 0, stream>>>(src, deg);
  scan_k<<<1, 1024, 0, stream>>>(deg, rowstart, cursor);
  scatter_k<<<N_EDGES / 256, 256, 0, stream>>>(src, cursor, csr);

  // QKVI = x @ [Wq|Wk|Wv|Wi] + bcat
  gemm3_k<<<dim3(8, 32), 256, 0, stream>>>(x, WcatT, bcat, QKVI, 1024);

  // edge_out = edge_attr @ We + be
  gemm3_k<<<dim3(2, 1024), 256, 0, stream>>>(ea, WeT, be, outE, 256);

  // fused logits + softmax + V aggregation (wave per node)
  node_attn_k<<<N_NODES / 4, 256, 0, stream>>>(QKVI, outE, rowstart, csr, tgt, agg);

  // preo = agg @ Wo + bo
  gemm3_k<<<dim3(2, 32), 256, 0, stream>>>(agg, WoT, bo, preo, 256);

  ln_k<<<N_NODES, 256, 0, stream>>>(QKVI, preo, lng, lnb, outN);
}

// Round 11
// 213.130 us; speedup vs baseline: 1.6251x; 1.0126x over previous
//
#include <hip/hip_runtime.h>

#define N_NODES 4096
#define N_EDGES 131072
#define DIM     256
#define HEADS   8
#define HDIM    32
#define MAXW    128      // per-node edge cap (Poisson λ=32; P(deg>128) ~ 1e-30)
#define MAXWP   132      // padded stride: (132h+t)%32 = 4h+t -> heads hit distinct banks

typedef unsigned short u16;
typedef unsigned int   u32;

using f32x4  = __attribute__((ext_vector_type(4))) float;
using bf16x8 = __attribute__((ext_vector_type(8))) short;
using u16x4  = __attribute__((ext_vector_type(4))) unsigned short;
using u16x8  = __attribute__((ext_vector_type(8))) unsigned short;

__device__ __forceinline__ u16 f2bf(float f) {
  u32 u = __float_as_uint(f);
  u += 0x7fffu + ((u >> 16) & 1u);   // RNE
  return (u16)(u >> 16);
}

__device__ __forceinline__ float dot4(float4 a, float4 b) {
  return a.x * b.x + a.y * b.y + a.z * b.z + a.w * b.w;
}

// ---------------------------------------------------------------------------
// Weight prep
// ---------------------------------------------------------------------------
__global__ __launch_bounds__(256) void prep_w_k(
    const float* __restrict__ Wq, const float* __restrict__ Wk,
    const float* __restrict__ Wv, const float* __restrict__ Wi,
    const float* __restrict__ We, const float* __restrict__ Wo,
    const float* __restrict__ bq, const float* __restrict__ bk,
    const float* __restrict__ bv, const float* __restrict__ bi,
    u16* __restrict__ WcatT, u16* __restrict__ WeT, u16* __restrict__ WoT,
    float* __restrict__ bcat)
{
  int n = blockIdx.x;
  int k = threadIdx.x;
  if (n < 1024) {
    const float* W = (n < 256) ? Wq : (n < 512) ? Wk : (n < 768) ? Wv : Wi;
    int nn = n & 255;
    WcatT[(size_t)n * 256 + k] = f2bf(W[(size_t)k * 256 + nn]);
    if (k == 0) {
      const float* b = (n < 256) ? bq : (n < 512) ? bk : (n < 768) ? bv : bi;
      bcat[n] = b[nn];
    }
  } else if (n < 1280) {
    int nn = n - 1024;
    WeT[(size_t)nn * 256 + k] = f2bf(We[(size_t)k * 256 + nn]);
  } else {
    int nn = n - 1280;
    WoT[(size_t)nn * 256 + k] = f2bf(Wo[(size_t)k * 256 + nn]);
  }
}

// ---------------------------------------------------------------------------
// 128x128 GEMM (proven 88us structure): C = A(fp32) @ B + bias, BT = B^T bf16.
// LDS dbuf, reg prefetch, lgkmcnt-only barrier, XOR swizzle. Lane holds
// C[m=mi*16+fr][n=ni*16+hi*4+reg] via mfma(b,a,acc) swap -> float4 stores.
// ---------------------------------------------------------------------------
__global__ __launch_bounds__(256) void gemm3_k(
    const float* __restrict__ Afp, const u16* __restrict__ BT,
    const float* __restrict__ bias, float* __restrict__ C, int Nn)
{
  __shared__ u16 As[2][128 * 32];
  __shared__ u16 Bs[2][128 * 32];
  const int n0 = blockIdx.x * 128;
  const int m0 = blockIdx.y * 128;
  const int tid = threadIdx.x;
  const int w = tid >> 6, l = tid & 63;
  const int wr = w >> 1, wc = w & 1;
  const int fr = l & 15, hi = l >> 4;

  float4 pa[4];
  u16x8  pb[2];
  f32x4  acc[4][4] = {};

  auto loadstep = [&](int kt) {
#pragma unroll
    for (int i = 0; i < 4; ++i) {
      int j = tid + 256 * i;
      pa[i] = *(const float4*)(Afp + (size_t)(m0 + (j >> 3)) * 256 + kt * 32 + ((j & 7) << 2));
    }
#pragma unroll
    for (int i = 0; i < 2; ++i) {
      int j = tid + 256 * i;
      pb[i] = *(const u16x8*)(BT + (size_t)(n0 + (j >> 2)) * 256 + kt * 32 + ((j & 3) << 3));
    }
  };
  auto storestep = [&](int buf) {
#pragma unroll
    for (int i = 0; i < 4; ++i) {
      int j = tid + 256 * i;
      int row = j >> 3;
      int c16 = (j & 7) >> 1, half = j & 1;
      int swc = (c16 + ((row >> 1) & 3)) & 3;
      u16x4 u;
      u.x = f2bf(pa[i].x); u.y = f2bf(pa[i].y); u.z = f2bf(pa[i].z); u.w = f2bf(pa[i].w);
      *(u16x4*)&As[buf][row * 32 + swc * 8 + half * 4] = u;
    }
#pragma unroll
    for (int i = 0; i < 2; ++i) {
      int j = tid + 256 * i;
      int row = j >> 2;
      int swc = ((j & 3) + ((row >> 1) & 3)) & 3;
      *(u16x8*)&Bs[buf][row * 32 + swc * 8] = pb[i];
    }
  };

  loadstep(0);
  storestep(0);

#pragma unroll
  for (int kt = 0; kt < 8; ++kt) {
    if (kt < 7) loadstep(kt + 1);
    __builtin_amdgcn_sched_barrier(0);
    asm volatile("s_waitcnt lgkmcnt(0)" ::: "memory");
    __builtin_amdgcn_s_barrier();
    __builtin_amdgcn_sched_barrier(0);
    const int cur = kt & 1;
    bf16x8 a[4], b[4];
#pragma unroll
    for (int mi = 0; mi < 4; ++mi) {
      int rA = wr * 64 + mi * 16 + fr;
      int swc = (hi + ((rA >> 1) & 3)) & 3;
      a[mi] = *(const bf16x8*)&As[cur][rA * 32 + swc * 8];
    }
#pragma unroll
    for (int ni = 0; ni < 4; ++ni) {
      int rB = wc * 64 + ni * 16 + fr;
      int swc = (hi + ((rB >> 1) & 3)) & 3;
      b[ni] = *(const bf16x8*)&Bs[cur][rB * 32 + swc * 8];
    }
#pragma unroll
    for (int mi = 0; mi < 4; ++mi)
#pragma unroll
      for (int ni = 0; ni < 4; ++ni)
        acc[mi][ni] = __builtin_amdgcn_mfma_f32_16x16x32_bf16(
            b[ni], a[mi], acc[mi][ni], 0, 0, 0);
    if (kt < 7) storestep((kt + 1) & 1);
  }

#pragma unroll
  for (int mi = 0; mi < 4; ++mi) {
    int row = m0 + wr * 64 + mi * 16 + fr;
#pragma unroll
    for (int ni = 0; ni < 4; ++ni) {
      int col = n0 + wc * 64 + ni * 16 + hi * 4;
      float4 bv = *(const float4*)&bias[col];
      f32x4 v = acc[mi][ni];
      float4 o;
      o.x = v[0] + bv.x; o.y = v[1] + bv.y; o.z = v[2] + bv.z; o.w = v[3] + bv.w;
      *(float4*)&C[(size_t)row * Nn + col] = o;
    }
  }
}

// ---------------------------------------------------------------------------
// CSR build
// ---------------------------------------------------------------------------
__global__ __launch_bounds__(256) void hist_k(const int* __restrict__ src, int* __restrict__ deg)
{
  int e = blockIdx.x * 256 + threadIdx.x;
  if (e < N_EDGES) atomicAdd(&deg[src[e]], 1);
}

__global__ __launch_bounds__(1024) void scan_k(const int* __restrict__ deg,
                                               int* __restrict__ rowstart,
                                               int* __restrict__ cursor)
{
  __shared__ int s[1024];
  int tid = threadIdx.x;
  int4 v = ((const int4*)deg)[tid];
  int sum = v.x + v.y + v.z + v.w;
  s[tid] = sum;
  __syncthreads();
  for (int off = 1; off < 1024; off <<= 1) {
    int t = (tid >= off) ? s[tid - off] : 0;
    __syncthreads();
    s[tid] += t;
    __syncthreads();
  }
  int excl = s[tid] - sum;
  int r0 = excl, r1 = excl + v.x, r2 = r1 + v.y, r3 = r2 + v.z;
  rowstart[4 * tid + 0] = r0; cursor[4 * tid + 0] = r0;
  rowstart[4 * tid + 1] = r1; cursor[4 * tid + 1] = r1;
  rowstart[4 * tid + 2] = r2; cursor[4 * tid + 2] = r2;
  rowstart[4 * tid + 3] = r3; cursor[4 * tid + 3] = r3;
  if (tid == 1023) rowstart[4096] = r3 + v.w;
}

__global__ __launch_bounds__(256) void scatter_k(const int* __restrict__ src,
                                                 int* __restrict__ cursor,
                                                 int* __restrict__ csr)
{
  int e = blockIdx.x * 256 + threadIdx.x;
  if (e < N_EDGES) {
    int p = atomicAdd(&cursor[src[e]], 1);
    csr[p] = e;
  }
}

// ---------------------------------------------------------------------------
// Wave-per-node fused kernel: edge logits + sparse softmax + V aggregation.
// 4 nodes per 256-thread block, one wave each. Lane l holds dims 4l..4l+3
// (head h = l>>3, 8 lanes/head). All reductions via 3-level __shfl_xor in
// the 8-lane group. Barriers only at 3 phase boundaries.
// ---------------------------------------------------------------------------
__global__ __launch_bounds__(256) void node_attn_k(
    const float* __restrict__ QKVI, const float* __restrict__ Ef,
    const int* __restrict__ rowstart, const int* __restrict__ csr,
    const int* __restrict__ tgt, float* __restrict__ agg)
{
  __shared__ int   s_eid[4][MAXW];
  __shared__ int   s_tgt[4][MAXW];
  __shared__ float s_sc[4][HEADS][MAXWP];
  __shared__ unsigned char s_alive[4][MAXW];
  __shared__ float s_self[4][8];
  __shared__ float s_wself[4][8];

  const float scl = 0.17677669529663687f;
  const int w = threadIdx.x >> 6, l = threadIdx.x & 63;
  const int i = blockIdx.x * 4 + w;
  const int h = l >> 3, d8 = l & 7;
  int base = rowstart[i];
  int deg = rowstart[i + 1] - base;
  if (deg > MAXW) deg = MAXW;

  for (int t = l; t < deg; t += 64) {
    int e = csr[base + t];
    s_eid[w][t] = e;
    s_tgt[w][t] = tgt[e];
  }
  __syncthreads();

  // Q_i: lane l holds dims 4l..4l+3
  float4 q4 = *(const float4*)&QKVI[(size_t)i * 1024 + 4 * l];

  // self score
  {
    float4 k4 = *(const float4*)&QKVI[(size_t)i * 1024 + 256 + 4 * l];
    float c = dot4(q4, k4);
    c += __shfl_xor(c, 1); c += __shfl_xor(c, 2); c += __shfl_xor(c, 4);
    if (d8 == 0) s_self[w][h] = c * scl;
  }

  // edge logits: whole wave per edge, 8 heads in parallel
  for (int t = 0; t < deg; ++t) {
    int e = s_eid[w][t], tt = s_tgt[w][t];
    float4 ef = *(const float4*)&Ef[(size_t)e * 256 + 4 * l];
    float4 k4 = *(const float4*)&QKVI[(size_t)tt * 1024 + 256 + 4 * l];
    float c = dot4(q4, ef) + dot4(ef, k4) + dot4(q4, k4);
    c += __shfl_xor(c, 1); c += __shfl_xor(c, 2); c += __shfl_xor(c, 4);
    if (d8 == 0) s_sc[w][h][t] = c * scl;
  }

  // dedup (keep max eid per tgt), drop self-target
  for (int t = l; t < deg; t += 64) {
    int tt = s_tgt[w][t], ee = s_eid[w][t];
    bool alive = (tt != i);
    if (alive)
      for (int u = 0; u < deg; ++u)
        if (s_tgt[w][u] == tt && s_eid[w][u] > ee) { alive = false; break; }
    s_alive[w][t] = alive ? 1 : 0;
  }
  __syncthreads();

  // softmax: 8 lanes per head
  {
    float m = s_self[w][h];
    for (int t = d8; t < deg; t += 8)
      if (s_alive[w][t]) m = fmaxf(m, s_sc[w][h][t]);
    m = fmaxf(m, __shfl_xor(m, 1)); m = fmaxf(m, __shfl_xor(m, 2)); m = fmaxf(m, __shfl_xor(m, 4));
    float lsum = 0.f;
    for (int t = d8; t < deg; t += 8) {
      float wv = s_alive[w][t] ? expf(s_sc[w][h][t] - m) : 0.f;
      s_sc[w][h][t] = wv;
      lsum += wv;
    }
    lsum += __shfl_xor(lsum, 1); lsum += __shfl_xor(lsum, 2); lsum += __shfl_xor(lsum, 4);
    float wself = expf(s_self[w][h] - m);
    float inv = 1.f / (lsum + wself);
    if (d8 == 0) s_wself[w][h] = wself * inv;
    for (int t = d8; t < deg; t += 8) s_sc[w][h][t] *= inv;
  }
  __syncthreads();

  // aggregate V: lane l accumulates cols 4l..4l+3 as float4
  float4 vv = *(const float4*)&QKVI[(size_t)i * 1024 + 512 + 4 * l];
  float ws = s_wself[w][h];
  float a0 = ws * vv.x, a1 = ws * vv.y, a2 = ws * vv.z, a3 = ws * vv.w;
  for (int t = 0; t < deg; ++t) {
    if (s_alive[w][t]) {
      float wt = s_sc[w][h][t];   // broadcast within 8-lane group
      float4 v4 = *(const float4*)&QKVI[(size_t)s_tgt[w][t] * 1024 + 512 + 4 * l];
      a0 += wt * v4.x; a1 += wt * v4.y; a2 += wt * v4.z; a3 += wt * v4.w;
    }
  }
  float4 o; o.x = a0; o.y = a1; o.z = a2; o.w = a3;
  *(float4*)&agg[(size_t)i * 256 + 4 * l] = o;
}

// ---------------------------------------------------------------------------
// LayerNorm(x_proj + preo)
// ---------------------------------------------------------------------------
__global__ __launch_bounds__(256) void ln_k(
    const float* __restrict__ QKVI, const float* __restrict__ preo,
    const float* __restrict__ g, const float* __restrict__ b,
    float* __restrict__ out)
{
  int i = blockIdx.x, c = threadIdx.x;
  float v = QKVI[(size_t)i * 1024 + 768 + c] + preo[(size_t)i * 256 + c];
  float s1 = v, s2 = v * v;
#pragma unroll
  for (int off = 32; off > 0; off >>= 1) {
    s1 += __shfl_xor(s1, off, 64);
    s2 += __shfl_xor(s2, off, 64);
  }
  __shared__ float r1[4], r2[4];
  int w = c >> 6;
  if ((c & 63) == 0) { r1[w] = s1; r2[w] = s2; }
  __syncthreads();
  s1 = r1[0] + r1[1] + r1[2] + r1[3];
  s2 = r2[0] + r2[1] + r2[2] + r2[3];
  float mu  = s1 * (1.0f / 256.0f);
  float var = s2 * (1.0f / 256.0f) - mu * mu;
  out[(size_t)i * 256 + c] = (v - mu) * rsqrtf(var + 1e-5f) * g[c] + b[c];
}

// ---------------------------------------------------------------------------
extern "C" void kernel_launch(void* const* d_in, const int* in_sizes, int n_in,
                              void* d_out, int out_size, void* d_ws, size_t ws_size,
                              hipStream_t stream) {
  (void)in_sizes; (void)n_in; (void)out_size; (void)ws_size;
  const float* x  = (const float*)d_in[0];
  const int*   ei = (const int*)d_in[1];
  const float* ea = (const float*)d_in[2];
  const float* Wq = (const float*)d_in[3];  const float* bq = (const float*)d_in[4];
  const float* Wk = (const float*)d_in[5];  const float* bk = (const float*)d_in[6];
  const float* Wv = (const float*)d_in[7];  const float* bv = (const float*)d_in[8];
  const float* We = (const float*)d_in[9];  const float* be = (const float*)d_in[10];
  const float* Wo = (const float*)d_in[11]; const float* bo = (const float*)d_in[12];
  const float* Wi = (const float*)d_in[13]; const float* bi = (const float*)d_in[14];
  const float* lng = (const float*)d_in[15]; const float* lnb = (const float*)d_in[16];

  const int* src = ei;
  const int* tgt = ei + N_EDGES;

  char* ws = (char*)d_ws;
  u16*   WcatT   = (u16*)(ws + 0);              //  512 KB
  u16*   WeT     = (u16*)(ws + 524288);         //  128 KB
  u16*   WoT     = (u16*)(ws + 655360);         //  128 KB
  float* bcat    = (float*)(ws + 786432);       //    4 KB
  float* QKVI    = (float*)(ws + 790528);       //   16 MB
  int*   deg     = (int*)(ws + 17567744);       //   16 KB
  int*   rowstart= (int*)(ws + 17584128);       //   16.25 KB
  int*   cursor  = (int*)(ws + 17600768);       //   16 KB
  int*   csr     = (int*)(ws + 17617152);       //  512 KB
  float* agg     = (float*)(ws + 18141440);     //    4 MB
  float* preo    = (float*)(ws + 22335744);     //    4 MB

  float* outN = (float*)d_out;
  float* outE = (float*)d_out + (size_t)N_NODES * DIM;

  (void)hipMemsetAsync(deg, 0, N_NODES * sizeof(int), stream);

  prep_w_k<<<1536, 256, 0, stream>>>(Wq, Wk, Wv, Wi, We, Wo, bq, bk, bv, bi,
                                     WcatT, WeT, WoT, bcat);

  hist_k<<<N_EDGES / 256, 256, 0, stream>>>(src, deg);
  scan_k<<<1, 1024, 0, stream>>>(deg, rowstart, cursor);
  scatter_k<<<N_EDGES / 256, 256, 0, stream>>>(src, cursor, csr);

  // QKVI = x @ [Wq|Wk|Wv|Wi] + bcat
  gemm3_k<<<dim3(8, 32), 256, 0, stream>>>(x, WcatT, bcat, QKVI, 1024);

  // edge_out = edge_attr @ We + be
  gemm3_k<<<dim3(2, 1024), 256, 0, stream>>>(ea, WeT, be, outE, 256);

  // fused logits + softmax + V aggregation (wave per node)
  node_attn_k<<<N_NODES / 4, 256, 0, stream>>>(QKVI, outE, rowstart, csr, tgt, agg);

  // preo = agg @ Wo + bo
  gemm3_k<<<dim3(2, 32), 256, 0, stream>>>(agg, WoT, bo, preo, 256);

  ln_k<<<N_NODES, 256, 0, stream>>>(QKVI, preo, lng, lnb, outN);
}